// Round 1
// baseline (1781.416 us; speedup 1.0000x reference)
//
#include <hip/hip_runtime.h>

constexpr int BATCH = 4;
constexpr int SEQ   = 2048;
constexpr int DM    = 1024;
constexpr int NQH   = 16;
constexpr int NKVH  = 4;
constexpr int HD    = 64;
constexpr int KVOUT = 2 * NKVH * HD;   // 512
constexpr int BT    = BATCH * SEQ;     // 8192

#define TM  128   // GEMM M/N tile
#define TKT 16    // GEMM K tile

// XOR-swizzle for 64-float-row LDS tiles: permute 16B chunks within a row by row&7.
// Keeps 16B alignment; makes stride-4-row ds_read_b128 patterns <=2-way (free).
__device__ __forceinline__ int swz(int row, int col) {
    return row * 64 + ((((col >> 2) ^ (row & 7)) << 2) | (col & 3));
}

// ---------------------------------------------------------------------------
// Fused GEMM (+ optional RoPE/QKV-scatter epilogue).
// QKV=true : out0=q_ws [B][NQH][SEQ][HD] (RoPE, *scale), kws/vws [B][NKVH][SEQ][HD]
// QKV=false: plain C = A@W0 into out0 [BT][DM]
// ---------------------------------------------------------------------------
template<bool QKV>
__global__ __launch_bounds__(256)
void gemm_rope_kernel(const float* __restrict__ A,     // [BT][DM]
                      const float* __restrict__ W0,    // [DM][DM]
                      const float* __restrict__ Wkv,   // [DM][KVOUT]
                      const float* __restrict__ cosb,  // [SEQ][HD]
                      const float* __restrict__ sinb,  // [SEQ][HD]
                      float* __restrict__ out0,
                      float* __restrict__ kws,
                      float* __restrict__ vws)
{
    __shared__ float As[TKT][TM + 4];   // stored transposed: As[k][m]
    __shared__ float Bs[TKT][TM + 4];

    const int tid = threadIdx.x;
    const int tx = tid & 15, ty = tid >> 4;
    const int m0 = blockIdx.y * TM;
    const int n0 = blockIdx.x * TM;

    const float* Wb; int ldb;
    if (!QKV || n0 < DM) { Wb = W0 + n0; ldb = DM; }
    else                 { Wb = Wkv + (n0 - DM); ldb = KVOUT; }

    float acc[8][8];
    #pragma unroll
    for (int i = 0; i < 8; i++)
        #pragma unroll
        for (int j = 0; j < 8; j++) acc[i][j] = 0.f;

    for (int k0 = 0; k0 < DM; k0 += TKT) {
        // stage A tile (128 rows x 16 k) transposed into As[k][m]
        #pragma unroll
        for (int i = 0; i < 2; i++) {
            int idx = tid + i * 256;            // 0..511
            int m   = idx >> 2;                 // 0..127
            int kc  = (idx & 3) << 2;           // 0,4,8,12
            float4 av = *reinterpret_cast<const float4*>(
                &A[(size_t)(m0 + m) * DM + k0 + kc]);
            As[kc + 0][m] = av.x; As[kc + 1][m] = av.y;
            As[kc + 2][m] = av.z; As[kc + 3][m] = av.w;
        }
        // stage B tile (16 k x 128 n)
        #pragma unroll
        for (int i = 0; i < 2; i++) {
            int idx = tid + i * 256;
            int kk  = idx >> 5;                 // 0..15
            int nc  = (idx & 31) << 2;          // 0..124
            *reinterpret_cast<float4*>(&Bs[kk][nc]) =
                *reinterpret_cast<const float4*>(&Wb[(size_t)(k0 + kk) * ldb + nc]);
        }
        __syncthreads();

        #pragma unroll
        for (int kk = 0; kk < TKT; kk++) {
            float a[8], b[8];
            *reinterpret_cast<float4*>(&a[0]) = *reinterpret_cast<const float4*>(&As[kk][ty * 8]);
            *reinterpret_cast<float4*>(&a[4]) = *reinterpret_cast<const float4*>(&As[kk][ty * 8 + 4]);
            *reinterpret_cast<float4*>(&b[0]) = *reinterpret_cast<const float4*>(&Bs[kk][tx * 8]);
            *reinterpret_cast<float4*>(&b[4]) = *reinterpret_cast<const float4*>(&Bs[kk][tx * 8 + 4]);
            #pragma unroll
            for (int i = 0; i < 8; i++)
                #pragma unroll
                for (int j = 0; j < 8; j++)
                    acc[i][j] = fmaf(a[i], b[j], acc[i][j]);
        }
        __syncthreads();
    }

    const float scale = 0.125f;  // 1/sqrt(HD), folded into q only
    if constexpr (QKV) {
        #pragma unroll
        for (int i = 0; i < 8; i++) {
            int m  = m0 + ty * 8 + i;
            int bb = m >> 11;            // / SEQ
            int t  = m & (SEQ - 1);
            int n  = n0 + tx * 8;
            if (n < DM) {                // ---- q: RoPE + scale ----
                int h = n >> 6, d0 = n & 63;
                float r[8];
                #pragma unroll
                for (int j = 0; j < 8; j += 2) {
                    float cc = cosb[t * HD + d0 + j];
                    float ss = sinb[t * HD + d0 + j];
                    float e = acc[i][j], od = acc[i][j + 1];
                    r[j]     = (e * cc - od * ss) * scale;
                    r[j + 1] = (od * cc + e * ss) * scale;
                }
                float* dst = out0 + (((size_t)bb * NQH + h) * SEQ + t) * HD + d0;
                *reinterpret_cast<float4*>(dst)     = make_float4(r[0], r[1], r[2], r[3]);
                *reinterpret_cast<float4*>(dst + 4) = make_float4(r[4], r[5], r[6], r[7]);
            } else {
                int nk  = n - DM;
                int kvh = nk >> 7;        // / (2*HD)
                int rem = nk & 127;
                if (rem < HD) {           // ---- k: RoPE, no scale ----
                    int d0 = rem;
                    float r[8];
                    #pragma unroll
                    for (int j = 0; j < 8; j += 2) {
                        float cc = cosb[t * HD + d0 + j];
                        float ss = sinb[t * HD + d0 + j];
                        float e = acc[i][j], od = acc[i][j + 1];
                        r[j]     = e * cc - od * ss;
                        r[j + 1] = od * cc + e * ss;
                    }
                    float* dst = kws + (((size_t)bb * NKVH + kvh) * SEQ + t) * HD + d0;
                    *reinterpret_cast<float4*>(dst)     = make_float4(r[0], r[1], r[2], r[3]);
                    *reinterpret_cast<float4*>(dst + 4) = make_float4(r[4], r[5], r[6], r[7]);
                } else {                  // ---- v: passthrough ----
                    int d0 = rem - HD;
                    float* dst = vws + (((size_t)bb * NKVH + kvh) * SEQ + t) * HD + d0;
                    *reinterpret_cast<float4*>(dst)     = make_float4(acc[i][0], acc[i][1], acc[i][2], acc[i][3]);
                    *reinterpret_cast<float4*>(dst + 4) = make_float4(acc[i][4], acc[i][5], acc[i][6], acc[i][7]);
                }
            }
        }
    } else {
        #pragma unroll
        for (int i = 0; i < 8; i++) {
            int m = m0 + ty * 8 + i;
            float* dst = out0 + (size_t)m * DM + n0 + tx * 8;
            *reinterpret_cast<float4*>(dst)     = make_float4(acc[i][0], acc[i][1], acc[i][2], acc[i][3]);
            *reinterpret_cast<float4*>(dst + 4) = make_float4(acc[i][4], acc[i][5], acc[i][6], acc[i][7]);
        }
    }
}

// ---------------------------------------------------------------------------
// Flash attention, fp32. Block = (q-tile of 64 rows) x (b,h). KV tiles of 64.
// Thread (tx,ty): S rows ty*4+i, S cols tx+16*j (strided -> conflict-free K reads),
// O rows ty*4+i, O cols tx*4+j. Row softmax stats via 16-lane shfl_xor.
// ---------------------------------------------------------------------------
__global__ __launch_bounds__(256)
void attn_kernel(const float* __restrict__ qws,
                 const float* __restrict__ kws,
                 const float* __restrict__ vws,
                 float* __restrict__ ao)          // [BT][DM], col = h*HD+d
{
    __shared__ float Qs[64 * 64];
    __shared__ float Ks[64 * 64];
    __shared__ float Vs[64 * 64];
    __shared__ float Ps[64 * 64];

    const int tid = threadIdx.x;
    const int tx = tid & 15, ty = tid >> 4;
    const int qt = blockIdx.x;
    const int bh = blockIdx.y;
    const int bb = bh >> 4;
    const int h  = bh & 15;
    const int kvh = h >> 2;   // GQA: 4 q-heads per kv-head

    const float* qbase = qws + (((size_t)bb * NQH + h) * SEQ + qt * 64) * HD;
    const float* kbase = kws + ((size_t)bb * NKVH + kvh) * SEQ * HD;
    const float* vbase = vws + ((size_t)bb * NKVH + kvh) * SEQ * HD;

    #pragma unroll
    for (int i = 0; i < 4; i++) {
        int idx = tid + i * 256;
        int r = idx >> 4;
        int c = (idx & 15) << 2;
        *reinterpret_cast<float4*>(&Qs[swz(r, c)]) =
            *reinterpret_cast<const float4*>(&qbase[r * HD + c]);
    }

    float mrow[4], lrow[4], o[4][4];
    #pragma unroll
    for (int i = 0; i < 4; i++) {
        mrow[i] = -1e30f; lrow[i] = 0.f;
        #pragma unroll
        for (int j = 0; j < 4; j++) o[i][j] = 0.f;
    }

    for (int kt = 0; kt < SEQ / 64; kt++) {
        __syncthreads();   // prev iter PV readers done before overwriting K/V
        const float* kp = kbase + (size_t)kt * 64 * HD;
        const float* vp = vbase + (size_t)kt * 64 * HD;
        #pragma unroll
        for (int i = 0; i < 4; i++) {
            int idx = tid + i * 256;
            int r = idx >> 4;
            int c = (idx & 15) << 2;
            *reinterpret_cast<float4*>(&Ks[swz(r, c)]) =
                *reinterpret_cast<const float4*>(&kp[r * HD + c]);
            *reinterpret_cast<float4*>(&Vs[swz(r, c)]) =
                *reinterpret_cast<const float4*>(&vp[r * HD + c]);
        }
        __syncthreads();

        // ---- S = q @ k^T  (q already scaled) ----
        float s[4][4];
        #pragma unroll
        for (int i = 0; i < 4; i++)
            #pragma unroll
            for (int j = 0; j < 4; j++) s[i][j] = 0.f;

        for (int d = 0; d < HD; d += 4) {
            float qa[4][4], ka[4][4];
            #pragma unroll
            for (int i = 0; i < 4; i++)
                *reinterpret_cast<float4*>(qa[i]) =
                    *reinterpret_cast<const float4*>(&Qs[swz(ty * 4 + i, d)]);
            #pragma unroll
            for (int j = 0; j < 4; j++)
                *reinterpret_cast<float4*>(ka[j]) =
                    *reinterpret_cast<const float4*>(&Ks[swz(tx + 16 * j, d)]);
            #pragma unroll
            for (int i = 0; i < 4; i++)
                #pragma unroll
                for (int j = 0; j < 4; j++)
                    #pragma unroll
                    for (int d2 = 0; d2 < 4; d2++)
                        s[i][j] = fmaf(qa[i][d2], ka[j][d2], s[i][j]);
        }

        // ---- online softmax (rows spread over 16 lanes of tx) ----
        #pragma unroll
        for (int i = 0; i < 4; i++) {
            float mx = fmaxf(fmaxf(s[i][0], s[i][1]), fmaxf(s[i][2], s[i][3]));
            #pragma unroll
            for (int off = 1; off < 16; off <<= 1) mx = fmaxf(mx, __shfl_xor(mx, off));
            float mnew = fmaxf(mrow[i], mx);
            float corr = __expf(mrow[i] - mnew);
            float psum = 0.f;
            #pragma unroll
            for (int j = 0; j < 4; j++) { s[i][j] = __expf(s[i][j] - mnew); psum += s[i][j]; }
            #pragma unroll
            for (int off = 1; off < 16; off <<= 1) psum += __shfl_xor(psum, off);
            lrow[i] = lrow[i] * corr + psum;
            mrow[i] = mnew;
            #pragma unroll
            for (int j = 0; j < 4; j++) o[i][j] *= corr;
            #pragma unroll
            for (int j = 0; j < 4; j++) Ps[swz(ty * 4 + i, tx + 16 * j)] = s[i][j];
        }
        __syncthreads();

        // ---- O += P @ V ----
        for (int kv0 = 0; kv0 < 64; kv0 += 4) {
            float pa[4][4], va[4][4];
            #pragma unroll
            for (int i = 0; i < 4; i++)
                *reinterpret_cast<float4*>(pa[i]) =
                    *reinterpret_cast<const float4*>(&Ps[swz(ty * 4 + i, kv0)]);
            #pragma unroll
            for (int k2 = 0; k2 < 4; k2++)
                *reinterpret_cast<float4*>(va[k2]) =
                    *reinterpret_cast<const float4*>(&Vs[swz(kv0 + k2, tx * 4)]);
            #pragma unroll
            for (int i = 0; i < 4; i++)
                #pragma unroll
                for (int k2 = 0; k2 < 4; k2++)
                    #pragma unroll
                    for (int j = 0; j < 4; j++)
                        o[i][j] = fmaf(pa[i][k2], va[k2][j], o[i][j]);
        }
    }

    #pragma unroll
    for (int i = 0; i < 4; i++) {
        float inv = 1.f / lrow[i];
        int row = bb * SEQ + qt * 64 + ty * 4 + i;
        float4 res = make_float4(o[i][0] * inv, o[i][1] * inv, o[i][2] * inv, o[i][3] * inv);
        *reinterpret_cast<float4*>(&ao[(size_t)row * DM + h * HD + tx * 4]) = res;
    }
}

// ---------------------------------------------------------------------------
extern "C" void kernel_launch(void* const* d_in, const int* in_sizes, int n_in,
                              void* d_out, int out_size, void* d_ws, size_t ws_size,
                              hipStream_t stream)
{
    const float* x    = (const float*)d_in[0];
    const float* cosb = (const float*)d_in[1];
    const float* sinb = (const float*)d_in[2];
    const float* Wq   = (const float*)d_in[3];
    const float* Wkv  = (const float*)d_in[4];
    const float* Wo   = (const float*)d_in[5];
    float* out = (float*)d_out;

    // workspace partition (floats): q 8388608 | k 2097152 | v 2097152 | ao 8388608
    float* qws = (float*)d_ws;
    float* kws = qws + (size_t)BT * DM;
    float* vws = kws + (size_t)BATCH * NKVH * SEQ * HD;
    float* ao  = vws + (size_t)BATCH * NKVH * SEQ * HD;

    dim3 g1((DM + KVOUT) / TM, BT / TM);   // (12, 64)
    gemm_rope_kernel<true><<<g1, 256, 0, stream>>>(x, Wq, Wkv, cosb, sinb, qws, kws, vws);

    dim3 g2(SEQ / 64, BATCH * NQH);        // (32, 64)
    attn_kernel<<<g2, 256, 0, stream>>>(qws, kws, vws, ao);

    dim3 g3(DM / TM, BT / TM);             // (8, 64)
    gemm_rope_kernel<false><<<g3, 256, 0, stream>>>(ao, Wo, nullptr, cosb, sinb, out, nullptr, nullptr);
}

// Round 2
// 942.520 us; speedup vs baseline: 1.8901x; 1.8901x over previous
//
#include <hip/hip_runtime.h>
#include <stdint.h>

constexpr int BATCH = 4;
constexpr int SEQ   = 2048;
constexpr int DM    = 1024;
constexpr int NQH   = 16;
constexpr int NKVH  = 4;
constexpr int HD    = 64;
constexpr int KVOUT = 2 * NKVH * HD;   // 512
constexpr int BT    = BATCH * SEQ;     // 8192

#define TM  128
#define TKT 16

typedef unsigned short u16;
typedef __attribute__((ext_vector_type(8))) short short8;
typedef __attribute__((ext_vector_type(8))) unsigned short u16x8;
typedef __attribute__((ext_vector_type(4))) float f32x4;
typedef __attribute__((ext_vector_type(4))) unsigned int u32x4;

// ---- bf16 split helpers (RNE) ----
__device__ __forceinline__ unsigned int bf_rne(float f) {
    unsigned int u = __float_as_uint(f);
    u += 0x7fffu + ((u >> 16) & 1u);
    return u >> 16;
}
__device__ __forceinline__ float from_bf(unsigned int h) {
    return __uint_as_float(h << 16);
}
__device__ __forceinline__ void split_bf(float f, u16& hi, u16& lo) {
    unsigned int h = bf_rne(f);
    hi = (u16)h;
    lo = (u16)bf_rne(f - from_bf(h));
}

__device__ __forceinline__ f32x4 mfma16(short8 a, short8 b, f32x4 c) {
    return __builtin_amdgcn_mfma_f32_16x16x32_bf16(a, b, c, 0, 0, 0);
}

typedef const __attribute__((address_space(1))) void gvoid_t;
typedef __attribute__((address_space(3))) void lvoid_t;

// ---------------------------------------------------------------------------
// Fused GEMM. QKV=true: epilogue does RoPE (+1/8 scale on q) and writes
// split-bf16 q/k (row-major [*,t,64]) and split-bf16 V TRANSPOSED [*,d,T].
// QKV=false: plain fp32 C = A@W0.
// ---------------------------------------------------------------------------
template<bool QKV>
__global__ __launch_bounds__(256)
void gemm_rope_kernel(const float* __restrict__ A,
                      const float* __restrict__ W0,
                      const float* __restrict__ Wkv,
                      const float* __restrict__ cosb,
                      const float* __restrict__ sinb,
                      float* __restrict__ out0,
                      u16* __restrict__ Qhi, u16* __restrict__ Qlo,
                      u16* __restrict__ Khi, u16* __restrict__ Klo,
                      u16* __restrict__ Vthi, u16* __restrict__ Vtlo)
{
    __shared__ float As[TKT][TM + 4];   // transposed: As[k][m]
    __shared__ float Bs[TKT][TM + 4];

    const int tid = threadIdx.x;
    const int tx = tid & 15, ty = tid >> 4;
    const int m0 = blockIdx.y * TM;
    const int n0 = blockIdx.x * TM;

    const float* Wb; int ldb;
    if (!QKV || n0 < DM) { Wb = W0 + n0; ldb = DM; }
    else                 { Wb = Wkv + (n0 - DM); ldb = KVOUT; }

    float acc[8][8];
    #pragma unroll
    for (int i = 0; i < 8; i++)
        #pragma unroll
        for (int j = 0; j < 8; j++) acc[i][j] = 0.f;

    for (int k0 = 0; k0 < DM; k0 += TKT) {
        #pragma unroll
        for (int i = 0; i < 2; i++) {
            int idx = tid + i * 256;
            int m   = idx >> 2;
            int kc  = (idx & 3) << 2;
            float4 av = *reinterpret_cast<const float4*>(
                &A[(size_t)(m0 + m) * DM + k0 + kc]);
            As[kc + 0][m] = av.x; As[kc + 1][m] = av.y;
            As[kc + 2][m] = av.z; As[kc + 3][m] = av.w;
        }
        #pragma unroll
        for (int i = 0; i < 2; i++) {
            int idx = tid + i * 256;
            int kk  = idx >> 5;
            int nc  = (idx & 31) << 2;
            *reinterpret_cast<float4*>(&Bs[kk][nc]) =
                *reinterpret_cast<const float4*>(&Wb[(size_t)(k0 + kk) * ldb + nc]);
        }
        __syncthreads();

        #pragma unroll
        for (int kk = 0; kk < TKT; kk++) {
            float a[8], b[8];
            *reinterpret_cast<float4*>(&a[0]) = *reinterpret_cast<const float4*>(&As[kk][ty * 8]);
            *reinterpret_cast<float4*>(&a[4]) = *reinterpret_cast<const float4*>(&As[kk][ty * 8 + 4]);
            *reinterpret_cast<float4*>(&b[0]) = *reinterpret_cast<const float4*>(&Bs[kk][tx * 8]);
            *reinterpret_cast<float4*>(&b[4]) = *reinterpret_cast<const float4*>(&Bs[kk][tx * 8 + 4]);
            #pragma unroll
            for (int i = 0; i < 8; i++)
                #pragma unroll
                for (int j = 0; j < 8; j++)
                    acc[i][j] = fmaf(a[i], b[j], acc[i][j]);
        }
        __syncthreads();
    }

    if constexpr (QKV) {
        const float scale = 0.125f;
        const int mm0 = m0 + ty * 8;
        const int bb = mm0 >> 11;
        const int t0 = mm0 & (SEQ - 1);
        const int n  = n0 + tx * 8;
        if (n < DM) {                       // ---- q: RoPE + scale, split ----
            int h = n >> 6, d0 = n & 63;
            size_t base = ((size_t)(bb * NQH + h) * SEQ + t0) * HD + d0;
            #pragma unroll
            for (int i = 0; i < 8; i++) {
                u16x8 vh, vl;
                #pragma unroll
                for (int j = 0; j < 8; j += 2) {
                    float cc = cosb[(t0 + i) * HD + d0 + j];
                    float ss = sinb[(t0 + i) * HD + d0 + j];
                    float e = acc[i][j], od = acc[i][j + 1];
                    u16 h0, l0, h1, l1;
                    split_bf((e * cc - od * ss) * scale, h0, l0);
                    split_bf((od * cc + e * ss) * scale, h1, l1);
                    vh[j] = h0; vl[j] = l0; vh[j + 1] = h1; vl[j + 1] = l1;
                }
                *reinterpret_cast<u16x8*>(&Qhi[base + (size_t)i * HD]) = vh;
                *reinterpret_cast<u16x8*>(&Qlo[base + (size_t)i * HD]) = vl;
            }
        } else {
            int nk = n - DM, kvh = nk >> 7, rem = nk & 127;
            if (rem < HD) {                 // ---- k: RoPE, split ----
                int d0 = rem;
                size_t base = ((size_t)(bb * NKVH + kvh) * SEQ + t0) * HD + d0;
                #pragma unroll
                for (int i = 0; i < 8; i++) {
                    u16x8 vh, vl;
                    #pragma unroll
                    for (int j = 0; j < 8; j += 2) {
                        float cc = cosb[(t0 + i) * HD + d0 + j];
                        float ss = sinb[(t0 + i) * HD + d0 + j];
                        float e = acc[i][j], od = acc[i][j + 1];
                        u16 h0, l0, h1, l1;
                        split_bf(e * cc - od * ss, h0, l0);
                        split_bf(od * cc + e * ss, h1, l1);
                        vh[j] = h0; vl[j] = l0; vh[j + 1] = h1; vl[j + 1] = l1;
                    }
                    *reinterpret_cast<u16x8*>(&Khi[base + (size_t)i * HD]) = vh;
                    *reinterpret_cast<u16x8*>(&Klo[base + (size_t)i * HD]) = vl;
                }
            } else {                        // ---- v: split, store transposed [d][T] ----
                int d0 = rem - HD;
                size_t vb = (size_t)(bb * NKVH + kvh) * HD + d0;
                #pragma unroll
                for (int j = 0; j < 8; j++) {
                    u16x8 vh, vl;
                    #pragma unroll
                    for (int i = 0; i < 8; i++) {
                        u16 h_, l_;
                        split_bf(acc[i][j], h_, l_);
                        vh[i] = h_; vl[i] = l_;
                    }
                    *reinterpret_cast<u16x8*>(&Vthi[(vb + j) * SEQ + t0]) = vh;
                    *reinterpret_cast<u16x8*>(&Vtlo[(vb + j) * SEQ + t0]) = vl;
                }
            }
        }
    } else {
        #pragma unroll
        for (int i = 0; i < 8; i++) {
            int m = m0 + ty * 8 + i;
            float* dst = out0 + (size_t)m * DM + n0 + tx * 8;
            *reinterpret_cast<float4*>(dst)     = make_float4(acc[i][0], acc[i][1], acc[i][2], acc[i][3]);
            *reinterpret_cast<float4*>(dst + 4) = make_float4(acc[i][4], acc[i][5], acc[i][6], acc[i][7]);
        }
    }
}

// ---------------------------------------------------------------------------
// MFMA flash attention, split-bf16 (3-product). Block = 64 q-rows x (b,h).
// 4 waves; wave w owns q-rows w*16..w*16+15. KV tiles of 64.
// K LDS [kv][64], Vt LDS [d][64kv], both hi/lo bf16, 16B-chunk XOR swizzle
// (c ^= row&7) realized by pre-swizzling the global_load_lds SOURCE address
// (LDS stays linear per-lane-contiguous, rule #21).
// ---------------------------------------------------------------------------
__global__ __launch_bounds__(256)
void attn_kernel(const u16* __restrict__ Qhi, const u16* __restrict__ Qlo,
                 const u16* __restrict__ Khi, const u16* __restrict__ Klo,
                 const u16* __restrict__ Vthi, const u16* __restrict__ Vtlo,
                 float* __restrict__ ao)
{
    __shared__ __align__(16) u16 Kh[64 * 64];
    __shared__ __align__(16) u16 Kl[64 * 64];
    __shared__ __align__(16) u16 Vh[64 * 64];
    __shared__ __align__(16) u16 Vl[64 * 64];
    __shared__ __align__(16) unsigned int Pb[4][16 * 64];   // packed hi|lo<<16, per wave

    const int tid  = threadIdx.x;
    const int lane = tid & 63;
    const int w    = tid >> 6;
    const int l15  = lane & 15;
    const int lg   = lane >> 4;          // 0..3

    const int qt  = blockIdx.x;
    const int bh  = blockIdx.y;
    const int bb  = bh >> 4, h = bh & 15;
    const int kvh = h >> 2;

    // Q A-fragments in registers: lane supplies row (w*16 + l15), k-chunk lg*8
    const size_t qoff = ((size_t)(bb * NQH + h) * SEQ + qt * 64 + w * 16 + l15) * HD + lg * 8;
    short8 qh[2], ql[2];
    qh[0] = *reinterpret_cast<const short8*>(Qhi + qoff);
    qh[1] = *reinterpret_cast<const short8*>(Qhi + qoff + 32);
    ql[0] = *reinterpret_cast<const short8*>(Qlo + qoff);
    ql[1] = *reinterpret_cast<const short8*>(Qlo + qoff + 32);

    // staging: wave w fills one buffer (8 x global_load_lds x 16B per lane)
    const u16* gb = (w == 0) ? Khi : (w == 1) ? Klo : (w == 2) ? Vthi : Vtlo;
    u16* lb       = (w == 0) ? Kh  : (w == 1) ? Kl  : (w == 2) ? Vh   : Vl;
    const bool isK = (w < 2);
    const size_t ktstep = isK ? (size_t)(64 * HD) : (size_t)64;
    size_t loff[8];
    {
        size_t kb = (size_t)(bb * NKVH + kvh) * SEQ;
        size_t vb = (size_t)(bb * NKVH + kvh) * HD;
        #pragma unroll
        for (int it = 0; it < 8; it++) {
            int nn = it * 64 + lane;
            int r  = nn >> 3, c = nn & 7;
            int sc = c ^ (r & 7);                    // pre-swizzled source chunk
            loff[it] = isK ? ((kb + r) * (size_t)HD + sc * 8)
                           : ((vb + r) * (size_t)SEQ + sc * 8);
        }
    }

    f32x4 oA[4] = {{0,0,0,0},{0,0,0,0},{0,0,0,0},{0,0,0,0}};
    float mrow[4] = {-1e30f,-1e30f,-1e30f,-1e30f};
    float lrow[4] = {0.f,0.f,0.f,0.f};

    for (int kt = 0; kt < SEQ / 64; kt++) {
        __syncthreads();                 // prior tile's LDS readers done
        #pragma unroll
        for (int it = 0; it < 8; it++) {
            __builtin_amdgcn_global_load_lds(
                (gvoid_t*)(gb + loff[it] + (size_t)kt * ktstep),
                (lvoid_t*)(lb + it * 512), 16, 0, 0);
        }
        __syncthreads();                 // vmcnt(0) drained before barrier

        // ---- S = Q K^T (3-product split) ----
        f32x4 sA[4];
        #pragma unroll
        for (int ct = 0; ct < 4; ct++) {
            f32x4 s = {0.f, 0.f, 0.f, 0.f};
            #pragma unroll
            for (int ks = 0; ks < 2; ks++) {
                int r = ct * 16 + l15;
                int c = (ks * 4 + lg) ^ (r & 7);
                short8 kh = *reinterpret_cast<const short8*>(Kh + r * 64 + c * 8);
                short8 kl = *reinterpret_cast<const short8*>(Kl + r * 64 + c * 8);
                s = mfma16(qh[ks], kh, s);
                s = mfma16(qh[ks], kl, s);
                s = mfma16(ql[ks], kh, s);
            }
            sA[ct] = s;
        }

        // ---- online softmax; lane's rows are lg*4+rr ----
        #pragma unroll
        for (int rr = 0; rr < 4; rr++) {
            float mx = fmaxf(fmaxf(sA[0][rr], sA[1][rr]), fmaxf(sA[2][rr], sA[3][rr]));
            mx = fmaxf(mx, __shfl_xor(mx, 1));
            mx = fmaxf(mx, __shfl_xor(mx, 2));
            mx = fmaxf(mx, __shfl_xor(mx, 4));
            mx = fmaxf(mx, __shfl_xor(mx, 8));
            float mnew = fmaxf(mrow[rr], mx);
            float corr = __expf(mrow[rr] - mnew);
            mrow[rr] = mnew;
            const int prow = lg * 4 + rr;
            float ps = 0.f;
            #pragma unroll
            for (int ct = 0; ct < 4; ct++) {
                float p = __expf(sA[ct][rr] - mnew);
                ps += p;
                unsigned int hb = bf_rne(p);
                unsigned int lbits = bf_rne(p - from_bf(hb));
                int colS = (ct * 16 + l15) ^ ((prow & 7) << 3);
                Pb[w][prow * 64 + colS] = hb | (lbits << 16);
            }
            ps += __shfl_xor(ps, 1);
            ps += __shfl_xor(ps, 2);
            ps += __shfl_xor(ps, 4);
            ps += __shfl_xor(ps, 8);
            lrow[rr] = lrow[rr] * corr + ps;
            oA[0][rr] *= corr; oA[1][rr] *= corr; oA[2][rr] *= corr; oA[3][rr] *= corr;
        }

        // ---- PV: A = P (rows l15), B = Vt ----
        short8 pah[2], pal[2];
        #pragma unroll
        for (int ks = 0; ks < 2; ks++) {
            int colS = (ks * 32 + lg * 8) ^ ((l15 & 7) << 3);
            const u32x4* pp = reinterpret_cast<const u32x4*>(&Pb[w][l15 * 64 + colS]);
            u32x4 u0 = pp[0], u1 = pp[1];
            #pragma unroll
            for (int j = 0; j < 4; j++) {
                pah[ks][j]     = (short)(u0[j] & 0xffffu);
                pal[ks][j]     = (short)(u0[j] >> 16);
                pah[ks][4 + j] = (short)(u1[j] & 0xffffu);
                pal[ks][4 + j] = (short)(u1[j] >> 16);
            }
        }
        #pragma unroll
        for (int dt = 0; dt < 4; dt++) {
            f32x4 o = oA[dt];
            #pragma unroll
            for (int ks = 0; ks < 2; ks++) {
                int d = dt * 16 + l15;
                int c = (ks * 4 + lg) ^ (d & 7);
                short8 vh = *reinterpret_cast<const short8*>(Vh + d * 64 + c * 8);
                short8 vl = *reinterpret_cast<const short8*>(Vl + d * 64 + c * 8);
                o = mfma16(pah[ks], vh, o);
                o = mfma16(pah[ks], vl, o);
                o = mfma16(pal[ks], vh, o);
            }
            oA[dt] = o;
        }
    }

    // epilogue: C layout row = lg*4+rr, col = dt*16+l15
    #pragma unroll
    for (int rr = 0; rr < 4; rr++) {
        float inv = 1.f / lrow[rr];
        int qrow = qt * 64 + w * 16 + lg * 4 + rr;
        size_t off = ((size_t)bb * SEQ + qrow) * DM + h * 64 + l15;
        #pragma unroll
        for (int dt = 0; dt < 4; dt++)
            ao[off + dt * 16] = oA[dt][rr] * inv;
    }
}

// ---------------------------------------------------------------------------
extern "C" void kernel_launch(void* const* d_in, const int* in_sizes, int n_in,
                              void* d_out, int out_size, void* d_ws, size_t ws_size,
                              hipStream_t stream)
{
    const float* x    = (const float*)d_in[0];
    const float* cosb = (const float*)d_in[1];
    const float* sinb = (const float*)d_in[2];
    const float* Wq   = (const float*)d_in[3];
    const float* Wkv  = (const float*)d_in[4];
    const float* Wo   = (const float*)d_in[5];
    float* out = (float*)d_out;

    // ws partition (83.9 MB total, same budget as round 1):
    char* p = (char*)d_ws;
    u16* Qhi = (u16*)p;  p += (size_t)BATCH * NQH  * SEQ * HD * 2;
    u16* Qlo = (u16*)p;  p += (size_t)BATCH * NQH  * SEQ * HD * 2;
    u16* Khi = (u16*)p;  p += (size_t)BATCH * NKVH * SEQ * HD * 2;
    u16* Klo = (u16*)p;  p += (size_t)BATCH * NKVH * SEQ * HD * 2;
    u16* Vthi = (u16*)p; p += (size_t)BATCH * NKVH * SEQ * HD * 2;
    u16* Vtlo = (u16*)p; p += (size_t)BATCH * NKVH * SEQ * HD * 2;
    float* ao = (float*)p;

    dim3 g1((DM + KVOUT) / TM, BT / TM);   // (12, 64)
    gemm_rope_kernel<true><<<g1, 256, 0, stream>>>(
        x, Wq, Wkv, cosb, sinb, nullptr, Qhi, Qlo, Khi, Klo, Vthi, Vtlo);

    dim3 g2(SEQ / 64, BATCH * NQH);        // (32, 64)
    attn_kernel<<<g2, 256, 0, stream>>>(Qhi, Qlo, Khi, Klo, Vthi, Vtlo, ao);

    dim3 g3(DM / TM, BT / TM);             // (8, 64)
    gemm_rope_kernel<false><<<g3, 256, 0, stream>>>(
        ao, Wo, nullptr, cosb, sinb, out,
        nullptr, nullptr, nullptr, nullptr, nullptr, nullptr);
}

// Round 3
// 641.115 us; speedup vs baseline: 2.7786x; 1.4701x over previous
//
#include <hip/hip_runtime.h>
#include <stdint.h>

constexpr int BATCH = 4;
constexpr int SEQ   = 2048;
constexpr int DM    = 1024;
constexpr int NQH   = 16;
constexpr int NKVH  = 4;
constexpr int HD    = 64;
constexpr int BT    = BATCH * SEQ;     // 8192

typedef unsigned short u16;
typedef __attribute__((ext_vector_type(4))) unsigned short u16x4;
typedef __attribute__((ext_vector_type(8))) short short8;
typedef __attribute__((ext_vector_type(4))) float f32x4;
typedef __attribute__((ext_vector_type(4))) unsigned int u32x4;

// ---- bf16 split helpers (RNE) ----
__device__ __forceinline__ unsigned int bf_rne(float f) {
    unsigned int u = __float_as_uint(f);
    u += 0x7fffu + ((u >> 16) & 1u);
    return u >> 16;
}
__device__ __forceinline__ float from_bf(unsigned int h) {
    return __uint_as_float(h << 16);
}
__device__ __forceinline__ void split_bf(float f, u16& hi, u16& lo) {
    unsigned int h = bf_rne(f);
    hi = (u16)h;
    lo = (u16)bf_rne(f - from_bf(h));
}

__device__ __forceinline__ f32x4 mfma16(short8 a, short8 b, f32x4 c) {
    return __builtin_amdgcn_mfma_f32_16x16x32_bf16(a, b, c, 0, 0, 0);
}

typedef const __attribute__((address_space(1))) void gvoid_t;
typedef __attribute__((address_space(3))) void lvoid_t;

// ---------------------------------------------------------------------------
// Transpose-split: src fp32 [K=1024 rows][ldn cols] -> dsthi/dstlo bf16 [N][1024].
// 64x64 padded-LDS tile transpose; both global accesses coalesced.
// ---------------------------------------------------------------------------
__global__ __launch_bounds__(256)
void tsplit_kernel(const float* __restrict__ src, int ldn,
                   u16* __restrict__ dsthi, u16* __restrict__ dstlo)
{
    __shared__ float tl[64][65];
    const int k0 = blockIdx.x * 64, n0 = blockIdx.y * 64;
    const int tid = threadIdx.x;
    #pragma unroll
    for (int p = 0; p < 16; p++) {
        int idx = tid + p * 256;
        int rr = idx >> 6, cc = idx & 63;
        tl[rr][cc] = src[(size_t)(k0 + rr) * ldn + n0 + cc];
    }
    __syncthreads();
    #pragma unroll
    for (int p = 0; p < 16; p++) {
        int idx = tid + p * 256;
        int rr = idx >> 6, cc = idx & 63;
        float v = tl[cc][rr];
        u16 h_, l_;
        split_bf(v, h_, l_);
        dsthi[(size_t)(n0 + rr) * 1024 + k0 + cc] = h_;
        dstlo[(size_t)(n0 + rr) * 1024 + k0 + cc] = l_;
    }
}

// ---------------------------------------------------------------------------
// Split-bf16 MFMA GEMM computing C^T: D[n][m] = sum_k WT[n][k] * X[m][k].
// 128x128 tile, BK=64, 4 waves (2x2), 4x4 fragments of 16x16x32 per wave.
// QKV=true : A=WTqkv [1536][1024] (gload), B=x fp32 (reg-split on the fly);
//            epilogue RoPE + split-scatter to Q/K/Vt.
// QKV=false: A=WoT [1024][1024], B=AO split pair (both gload); fp32 C out.
// LDS tiles [128][8 chunks of 16B], chunk XOR-swizzled by row&7.
// ---------------------------------------------------------------------------
template<bool QKV>
__global__ __launch_bounds__(256)
void gemm_mfma(const float* __restrict__ xf,
               const u16* __restrict__ WThi, const u16* __restrict__ WTlo,
               const u16* __restrict__ Bhi,  const u16* __restrict__ Blo,
               const float* __restrict__ cosb, const float* __restrict__ sinb,
               u16* __restrict__ Qhi, u16* __restrict__ Qlo,
               u16* __restrict__ Khi, u16* __restrict__ Klo,
               u16* __restrict__ Vthi, u16* __restrict__ Vtlo,
               float* __restrict__ out)
{
    __shared__ __align__(16) u16 Whs[128 * 64];
    __shared__ __align__(16) u16 Wls[128 * 64];
    __shared__ __align__(16) u16 Xhs[128 * 64];
    __shared__ __align__(16) u16 Xls[128 * 64];

    const int tid  = threadIdx.x;
    const int lane = tid & 63;
    const int w    = tid >> 6;
    const int l15  = lane & 15;
    const int lg   = lane >> 4;
    const int wn   = (w & 1) * 64;
    const int wm   = (w >> 1) * 64;
    const int n0   = blockIdx.x * 128;
    const int m0   = blockIdx.y * 128;

    f32x4 acc[4][4];
    #pragma unroll
    for (int i = 0; i < 4; i++)
        #pragma unroll
        for (int j = 0; j < 4; j++) acc[i][j] = f32x4{0.f, 0.f, 0.f, 0.f};

    for (int k0 = 0; k0 < DM; k0 += 64) {
        __syncthreads();
        if constexpr (QKV) {
            // ---- W side: 2 buffers staged by 4 waves via global_load_lds ----
            const u16* wsrc = (w < 2) ? WThi : WTlo;
            u16* wdst = (w < 2) ? Whs : Wls;
            #pragma unroll
            for (int it = 0; it < 8; it++) {
                int id = ((w & 1) << 9) | (it << 6) | lane;
                int r = id >> 3, c = id & 7;
                int sc = c ^ (r & 7);
                __builtin_amdgcn_global_load_lds(
                    (gvoid_t*)(wsrc + (size_t)(n0 + r) * 1024 + k0 + sc * 8),
                    (lvoid_t*)(wdst + id * 8), 16, 0, 0);
            }
            // ---- X side: fp32 -> split bf16, reg-staged with manual swizzle ----
            int rr = tid >> 1, half = tid & 1;
            const float* xp = xf + (size_t)(m0 + rr) * 1024 + k0 + half * 32;
            float fa[32];
            #pragma unroll
            for (int q = 0; q < 8; q++)
                *reinterpret_cast<float4*>(&fa[q * 4]) =
                    reinterpret_cast<const float4*>(xp)[q];
            #pragma unroll
            for (int c = 0; c < 4; c++) {
                short8 hi8, lo8;
                #pragma unroll
                for (int jj = 0; jj < 8; jj++) {
                    u16 h_, l_;
                    split_bf(fa[c * 8 + jj], h_, l_);
                    hi8[jj] = (short)h_; lo8[jj] = (short)l_;
                }
                int cc = half * 4 + c;
                int sc = cc ^ (rr & 7);
                *reinterpret_cast<short8*>(&Xhs[rr * 64 + sc * 8]) = hi8;
                *reinterpret_cast<short8*>(&Xls[rr * 64 + sc * 8]) = lo8;
            }
        } else {
            // ---- all 4 buffers via global_load_lds, one per wave ----
            const u16* src = (w == 0) ? WThi : (w == 1) ? WTlo : (w == 2) ? Bhi : Blo;
            u16* dst       = (w == 0) ? Whs  : (w == 1) ? Wls  : (w == 2) ? Xhs : Xls;
            int rbase = (w < 2) ? n0 : m0;
            #pragma unroll
            for (int it = 0; it < 16; it++) {
                int id = (it << 6) | lane;
                int r = id >> 3, c = id & 7;
                int sc = c ^ (r & 7);
                __builtin_amdgcn_global_load_lds(
                    (gvoid_t*)(src + (size_t)(rbase + r) * 1024 + k0 + sc * 8),
                    (lvoid_t*)(dst + id * 8), 16, 0, 0);
            }
        }
        __syncthreads();

        #pragma unroll
        for (int ks = 0; ks < 2; ks++) {
            short8 ah[4], al[4], bh[4], bl[4];
            #pragma unroll
            for (int i = 0; i < 4; i++) {
                int rn = wn + i * 16 + l15;
                int ch = ((ks << 2) + lg) ^ (rn & 7);
                ah[i] = *reinterpret_cast<const short8*>(&Whs[rn * 64 + ch * 8]);
                al[i] = *reinterpret_cast<const short8*>(&Wls[rn * 64 + ch * 8]);
            }
            #pragma unroll
            for (int j = 0; j < 4; j++) {
                int rm = wm + j * 16 + l15;
                int ch = ((ks << 2) + lg) ^ (rm & 7);
                bh[j] = *reinterpret_cast<const short8*>(&Xhs[rm * 64 + ch * 8]);
                bl[j] = *reinterpret_cast<const short8*>(&Xls[rm * 64 + ch * 8]);
            }
            #pragma unroll
            for (int i = 0; i < 4; i++)
                #pragma unroll
                for (int j = 0; j < 4; j++) {
                    acc[i][j] = mfma16(ah[i], bh[j], acc[i][j]);
                    acc[i][j] = mfma16(ah[i], bl[j], acc[i][j]);
                    acc[i][j] = mfma16(al[i], bh[j], acc[i][j]);
                }
        }
    }

    // ---- epilogue: D[n][m]; lane n = base+lg*4+reg (4 consecutive), m = +l15 ----
    if constexpr (QKV) {
        #pragma unroll
        for (int i = 0; i < 4; i++) {
            int nb = n0 + wn + i * 16 + lg * 4;
            if (nb < DM) {                       // ---- q: RoPE * 0.125 ----
                int hh = nb >> 6, d0 = nb & 63;
                #pragma unroll
                for (int j = 0; j < 4; j++) {
                    int m = m0 + wm + j * 16 + l15;
                    int bb = m >> 11, t = m & (SEQ - 1);
                    float4 c4 = *reinterpret_cast<const float4*>(&cosb[t * HD + d0]);
                    float4 s4 = *reinterpret_cast<const float4*>(&sinb[t * HD + d0]);
                    f32x4 a = acc[i][j];
                    float r0 = (a[0] * c4.x - a[1] * s4.x) * 0.125f;
                    float r1 = (a[1] * c4.x + a[0] * s4.x) * 0.125f;
                    float r2 = (a[2] * c4.z - a[3] * s4.z) * 0.125f;
                    float r3 = (a[3] * c4.z + a[2] * s4.z) * 0.125f;
                    u16 h0, l0, h1, l1, h2, l2, h3, l3;
                    split_bf(r0, h0, l0); split_bf(r1, h1, l1);
                    split_bf(r2, h2, l2); split_bf(r3, h3, l3);
                    size_t off = ((size_t)(bb * NQH + hh) * SEQ + t) * HD + d0;
                    *reinterpret_cast<u16x4*>(&Qhi[off]) = u16x4{h0, h1, h2, h3};
                    *reinterpret_cast<u16x4*>(&Qlo[off]) = u16x4{l0, l1, l2, l3};
                }
            } else {
                int rem = nb - DM;
                int kvh = rem >> 7, r2v = rem & 127;
                if (r2v < HD) {                  // ---- k: RoPE ----
                    int d0 = r2v;
                    #pragma unroll
                    for (int j = 0; j < 4; j++) {
                        int m = m0 + wm + j * 16 + l15;
                        int bb = m >> 11, t = m & (SEQ - 1);
                        float4 c4 = *reinterpret_cast<const float4*>(&cosb[t * HD + d0]);
                        float4 s4 = *reinterpret_cast<const float4*>(&sinb[t * HD + d0]);
                        f32x4 a = acc[i][j];
                        float r0 = a[0] * c4.x - a[1] * s4.x;
                        float r1 = a[1] * c4.x + a[0] * s4.x;
                        float r2 = a[2] * c4.z - a[3] * s4.z;
                        float r3 = a[3] * c4.z + a[2] * s4.z;
                        u16 h0, l0, h1, l1, h2, l2, h3, l3;
                        split_bf(r0, h0, l0); split_bf(r1, h1, l1);
                        split_bf(r2, h2, l2); split_bf(r3, h3, l3);
                        size_t off = ((size_t)(bb * NKVH + kvh) * SEQ + t) * HD + d0;
                        *reinterpret_cast<u16x4*>(&Khi[off]) = u16x4{h0, h1, h2, h3};
                        *reinterpret_cast<u16x4*>(&Klo[off]) = u16x4{l0, l1, l2, l3};
                    }
                } else {                         // ---- v: transposed scatter ----
                    int d0 = r2v - HD;
                    #pragma unroll
                    for (int j = 0; j < 4; j++) {
                        int m = m0 + wm + j * 16 + l15;
                        int bb = m >> 11, t = m & (SEQ - 1);
                        size_t vb = (size_t)(bb * NKVH + kvh) * HD;
                        #pragma unroll
                        for (int reg = 0; reg < 4; reg++) {
                            u16 hv, lv;
                            split_bf(acc[i][j][reg], hv, lv);
                            size_t off = (vb + d0 + reg) * SEQ + t;
                            Vthi[off] = hv; Vtlo[off] = lv;
                        }
                    }
                }
            }
        }
    } else {
        #pragma unroll
        for (int i = 0; i < 4; i++) {
            int nb = n0 + wn + i * 16 + lg * 4;
            #pragma unroll
            for (int j = 0; j < 4; j++) {
                int m = m0 + wm + j * 16 + l15;
                *reinterpret_cast<float4*>(&out[(size_t)m * DM + nb]) =
                    make_float4(acc[i][j][0], acc[i][j][1], acc[i][j][2], acc[i][j][3]);
            }
        }
    }
}

// ---------------------------------------------------------------------------
// MFMA flash attention, split-bf16 (unchanged core from R2); epilogue now
// writes AO as split bf16 for the Wo MFMA GEMM.
// ---------------------------------------------------------------------------
__global__ __launch_bounds__(256)
void attn_kernel(const u16* __restrict__ Qhi, const u16* __restrict__ Qlo,
                 const u16* __restrict__ Khi, const u16* __restrict__ Klo,
                 const u16* __restrict__ Vthi, const u16* __restrict__ Vtlo,
                 u16* __restrict__ AOhi, u16* __restrict__ AOlo)
{
    __shared__ __align__(16) u16 Kh[64 * 64];
    __shared__ __align__(16) u16 Kl[64 * 64];
    __shared__ __align__(16) u16 Vh[64 * 64];
    __shared__ __align__(16) u16 Vl[64 * 64];
    __shared__ __align__(16) unsigned int Pb[4][16 * 64];

    const int tid  = threadIdx.x;
    const int lane = tid & 63;
    const int w    = tid >> 6;
    const int l15  = lane & 15;
    const int lg   = lane >> 4;

    const int qt  = blockIdx.x;
    const int bh  = blockIdx.y;
    const int bb  = bh >> 4, h = bh & 15;
    const int kvh = h >> 2;

    const size_t qoff = ((size_t)(bb * NQH + h) * SEQ + qt * 64 + w * 16 + l15) * HD + lg * 8;
    short8 qh[2], ql[2];
    qh[0] = *reinterpret_cast<const short8*>(Qhi + qoff);
    qh[1] = *reinterpret_cast<const short8*>(Qhi + qoff + 32);
    ql[0] = *reinterpret_cast<const short8*>(Qlo + qoff);
    ql[1] = *reinterpret_cast<const short8*>(Qlo + qoff + 32);

    const u16* gb = (w == 0) ? Khi : (w == 1) ? Klo : (w == 2) ? Vthi : Vtlo;
    u16* lb       = (w == 0) ? Kh  : (w == 1) ? Kl  : (w == 2) ? Vh   : Vl;
    const bool isK = (w < 2);
    const size_t ktstep = isK ? (size_t)(64 * HD) : (size_t)64;
    size_t loff[8];
    {
        size_t kb = (size_t)(bb * NKVH + kvh) * SEQ;
        size_t vb = (size_t)(bb * NKVH + kvh) * HD;
        #pragma unroll
        for (int it = 0; it < 8; it++) {
            int nn = it * 64 + lane;
            int r  = nn >> 3, c = nn & 7;
            int sc = c ^ (r & 7);
            loff[it] = isK ? ((kb + r) * (size_t)HD + sc * 8)
                           : ((vb + r) * (size_t)SEQ + sc * 8);
        }
    }

    f32x4 oA[4] = {{0,0,0,0},{0,0,0,0},{0,0,0,0},{0,0,0,0}};
    float mrow[4] = {-1e30f,-1e30f,-1e30f,-1e30f};
    float lrow[4] = {0.f,0.f,0.f,0.f};

    for (int kt = 0; kt < SEQ / 64; kt++) {
        __syncthreads();
        #pragma unroll
        for (int it = 0; it < 8; it++) {
            __builtin_amdgcn_global_load_lds(
                (gvoid_t*)(gb + loff[it] + (size_t)kt * ktstep),
                (lvoid_t*)(lb + it * 512), 16, 0, 0);
        }
        __syncthreads();

        f32x4 sA[4];
        #pragma unroll
        for (int ct = 0; ct < 4; ct++) {
            f32x4 s = {0.f, 0.f, 0.f, 0.f};
            #pragma unroll
            for (int ks = 0; ks < 2; ks++) {
                int r = ct * 16 + l15;
                int c = (ks * 4 + lg) ^ (r & 7);
                short8 kh = *reinterpret_cast<const short8*>(Kh + r * 64 + c * 8);
                short8 kl = *reinterpret_cast<const short8*>(Kl + r * 64 + c * 8);
                s = mfma16(qh[ks], kh, s);
                s = mfma16(qh[ks], kl, s);
                s = mfma16(ql[ks], kh, s);
            }
            sA[ct] = s;
        }

        #pragma unroll
        for (int rr = 0; rr < 4; rr++) {
            float mx = fmaxf(fmaxf(sA[0][rr], sA[1][rr]), fmaxf(sA[2][rr], sA[3][rr]));
            mx = fmaxf(mx, __shfl_xor(mx, 1));
            mx = fmaxf(mx, __shfl_xor(mx, 2));
            mx = fmaxf(mx, __shfl_xor(mx, 4));
            mx = fmaxf(mx, __shfl_xor(mx, 8));
            float mnew = fmaxf(mrow[rr], mx);
            float corr = __expf(mrow[rr] - mnew);
            mrow[rr] = mnew;
            const int prow = lg * 4 + rr;
            float ps = 0.f;
            #pragma unroll
            for (int ct = 0; ct < 4; ct++) {
                float p = __expf(sA[ct][rr] - mnew);
                ps += p;
                unsigned int hb = bf_rne(p);
                unsigned int lbits = bf_rne(p - from_bf(hb));
                int colS = (ct * 16 + l15) ^ ((prow & 7) << 3);
                Pb[w][prow * 64 + colS] = hb | (lbits << 16);
            }
            ps += __shfl_xor(ps, 1);
            ps += __shfl_xor(ps, 2);
            ps += __shfl_xor(ps, 4);
            ps += __shfl_xor(ps, 8);
            lrow[rr] = lrow[rr] * corr + ps;
            oA[0][rr] *= corr; oA[1][rr] *= corr; oA[2][rr] *= corr; oA[3][rr] *= corr;
        }

        short8 pah[2], pal[2];
        #pragma unroll
        for (int ks = 0; ks < 2; ks++) {
            int colS = (ks * 32 + lg * 8) ^ ((l15 & 7) << 3);
            const u32x4* pp = reinterpret_cast<const u32x4*>(&Pb[w][l15 * 64 + colS]);
            u32x4 u0 = pp[0], u1 = pp[1];
            #pragma unroll
            for (int j = 0; j < 4; j++) {
                pah[ks][j]     = (short)(u0[j] & 0xffffu);
                pal[ks][j]     = (short)(u0[j] >> 16);
                pah[ks][4 + j] = (short)(u1[j] & 0xffffu);
                pal[ks][4 + j] = (short)(u1[j] >> 16);
            }
        }
        #pragma unroll
        for (int dt = 0; dt < 4; dt++) {
            f32x4 o = oA[dt];
            #pragma unroll
            for (int ks = 0; ks < 2; ks++) {
                int d = dt * 16 + l15;
                int c = (ks * 4 + lg) ^ (d & 7);
                short8 vh = *reinterpret_cast<const short8*>(Vh + d * 64 + c * 8);
                short8 vl = *reinterpret_cast<const short8*>(Vl + d * 64 + c * 8);
                o = mfma16(pah[ks], vh, o);
                o = mfma16(pah[ks], vl, o);
                o = mfma16(pal[ks], vh, o);
            }
            oA[dt] = o;
        }
    }

    #pragma unroll
    for (int rr = 0; rr < 4; rr++) {
        float inv = 1.f / lrow[rr];
        int qrow = qt * 64 + w * 16 + lg * 4 + rr;
        size_t off = ((size_t)bb * SEQ + qrow) * DM + h * 64 + l15;
        #pragma unroll
        for (int dt = 0; dt < 4; dt++) {
            float v = oA[dt][rr] * inv;
            unsigned int hb = bf_rne(v);
            AOhi[off + dt * 16] = (u16)hb;
            AOlo[off + dt * 16] = (u16)bf_rne(v - from_bf(hb));
        }
    }
}

// ---------------------------------------------------------------------------
extern "C" void kernel_launch(void* const* d_in, const int* in_sizes, int n_in,
                              void* d_out, int out_size, void* d_ws, size_t ws_size,
                              hipStream_t stream)
{
    const float* x    = (const float*)d_in[0];
    const float* cosb = (const float*)d_in[1];
    const float* sinb = (const float*)d_in[2];
    const float* Wq   = (const float*)d_in[3];
    const float* Wkv  = (const float*)d_in[4];
    const float* Wo   = (const float*)d_in[5];
    float* out = (float*)d_out;

    // ws (u16 units, 83.9 MB total — proven budget). Aliasing:
    //  [0 .. 16.8M)  : WTqkv pair (prep1..gemm1), then AO pair (attn..gemm2)
    //  [16.8M..33.6M): Q pair (gemm1..attn), then WoT pair (prep2..gemm2)
    //  [33.6M..41.9M): K pair, Vt pair
    u16* base  = (u16*)d_ws;
    u16* AOhi  = base;
    u16* AOlo  = base + 8388608;
    u16* WThi  = base;                      // alias over AO region
    u16* WTlo  = base + 1572864;
    u16* Qhi   = base + 16777216;
    u16* Qlo   = base + 25165824;
    u16* WoThi = base + 16777216;           // alias over Q region (post-attn)
    u16* WoTlo = base + 17825792;
    u16* Khi   = base + 33554432;
    u16* Klo   = base + 35651584;
    u16* Vthi  = base + 37748736;
    u16* Vtlo  = base + 39845888;

    tsplit_kernel<<<dim3(16, 16), 256, 0, stream>>>(Wq, 1024, WThi, WTlo);
    tsplit_kernel<<<dim3(16, 8),  256, 0, stream>>>(Wkv, 512, WThi + 1048576, WTlo + 1048576);

    gemm_mfma<true><<<dim3(12, 64), 256, 0, stream>>>(
        x, WThi, WTlo, nullptr, nullptr, cosb, sinb,
        Qhi, Qlo, Khi, Klo, Vthi, Vtlo, nullptr);

    attn_kernel<<<dim3(32, 64), 256, 0, stream>>>(
        Qhi, Qlo, Khi, Klo, Vthi, Vtlo, AOhi, AOlo);

    tsplit_kernel<<<dim3(16, 16), 256, 0, stream>>>(Wo, 1024, WoThi, WoTlo);

    gemm_mfma<false><<<dim3(8, 64), 256, 0, stream>>>(
        nullptr, WoThi, WoTlo, AOhi, AOlo, nullptr, nullptr,
        nullptr, nullptr, nullptr, nullptr, nullptr, nullptr, out);
}

// Round 6
// 594.543 us; speedup vs baseline: 2.9963x; 1.0783x over previous
//
#include <hip/hip_runtime.h>
#include <stdint.h>

constexpr int BATCH = 4;
constexpr int SEQ   = 2048;
constexpr int DM    = 1024;
constexpr int NQH   = 16;
constexpr int NKVH  = 4;
constexpr int HD    = 64;
constexpr int BT    = BATCH * SEQ;     // 8192

typedef unsigned short u16;
typedef __attribute__((ext_vector_type(4))) unsigned short u16x4;
typedef __attribute__((ext_vector_type(8))) short short8;
typedef __attribute__((ext_vector_type(4))) float f32x4;
typedef __attribute__((ext_vector_type(4))) unsigned int u32x4;

// ---- bf16 split helpers (RNE) ----
__device__ __forceinline__ unsigned int bf_rne(float f) {
    unsigned int u = __float_as_uint(f);
    u += 0x7fffu + ((u >> 16) & 1u);
    return u >> 16;
}
__device__ __forceinline__ float from_bf(unsigned int h) {
    return __uint_as_float(h << 16);
}
__device__ __forceinline__ void split_bf(float f, u16& hi, u16& lo) {
    unsigned int h = bf_rne(f);
    hi = (u16)h;
    lo = (u16)bf_rne(f - from_bf(h));
}

__device__ __forceinline__ f32x4 mfma16(short8 a, short8 b, f32x4 c) {
    return __builtin_amdgcn_mfma_f32_16x16x32_bf16(a, b, c, 0, 0, 0);
}

typedef const __attribute__((address_space(1))) void gvoid_t;
typedef __attribute__((address_space(3))) void lvoid_t;

// ---------------------------------------------------------------------------
// Transpose-split: src fp32 [K=1024 rows][ldn cols] -> dsthi/dstlo bf16 [N][1024].
// ---------------------------------------------------------------------------
__global__ __launch_bounds__(256)
void tsplit_kernel(const float* __restrict__ src, int ldn,
                   u16* __restrict__ dsthi, u16* __restrict__ dstlo)
{
    __shared__ float tl[64][65];
    const int k0 = blockIdx.x * 64, n0 = blockIdx.y * 64;
    const int tid = threadIdx.x;
    #pragma unroll
    for (int p = 0; p < 16; p++) {
        int idx = tid + p * 256;
        int rr = idx >> 6, cc = idx & 63;
        tl[rr][cc] = src[(size_t)(k0 + rr) * ldn + n0 + cc];
    }
    __syncthreads();
    #pragma unroll
    for (int p = 0; p < 16; p++) {
        int idx = tid + p * 256;
        int rr = idx >> 6, cc = idx & 63;
        float v = tl[cc][rr];
        u16 h_, l_;
        split_bf(v, h_, l_);
        dsthi[(size_t)(n0 + rr) * 1024 + k0 + cc] = h_;
        dstlo[(size_t)(n0 + rr) * 1024 + k0 + cc] = l_;
    }
}

// ---------------------------------------------------------------------------
// Split-bf16 MFMA GEMM computing C^T: D[n][m] = sum_k WT[n][k] * X[m][k].
// 4-product split (hh + hl + lh + ll): exact at split-representation level.
// ---------------------------------------------------------------------------
template<bool QKV>
__global__ __launch_bounds__(256)
void gemm_mfma(const float* __restrict__ xf,
               const u16* __restrict__ WThi, const u16* __restrict__ WTlo,
               const u16* __restrict__ Bhi,  const u16* __restrict__ Blo,
               const float* __restrict__ cosb, const float* __restrict__ sinb,
               u16* __restrict__ Qhi, u16* __restrict__ Qlo,
               u16* __restrict__ Khi, u16* __restrict__ Klo,
               u16* __restrict__ Vthi, u16* __restrict__ Vtlo,
               float* __restrict__ out)
{
    __shared__ __align__(16) u16 Whs[128 * 64];
    __shared__ __align__(16) u16 Wls[128 * 64];
    __shared__ __align__(16) u16 Xhs[128 * 64];
    __shared__ __align__(16) u16 Xls[128 * 64];

    const int tid  = threadIdx.x;
    const int lane = tid & 63;
    const int w    = tid >> 6;
    const int l15  = lane & 15;
    const int lg   = lane >> 4;
    const int wn   = (w & 1) * 64;
    const int wm   = (w >> 1) * 64;
    const int n0   = blockIdx.x * 128;
    const int m0   = blockIdx.y * 128;

    f32x4 acc[4][4];
    #pragma unroll
    for (int i = 0; i < 4; i++)
        #pragma unroll
        for (int j = 0; j < 4; j++) acc[i][j] = f32x4{0.f, 0.f, 0.f, 0.f};

    for (int k0 = 0; k0 < DM; k0 += 64) {
        __syncthreads();
        if constexpr (QKV) {
            const u16* wsrc = (w < 2) ? WThi : WTlo;
            u16* wdst = (w < 2) ? Whs : Wls;
            #pragma unroll
            for (int it = 0; it < 8; it++) {
                int id = ((w & 1) << 9) | (it << 6) | lane;
                int r = id >> 3, c = id & 7;
                int sc = c ^ (r & 7);
                __builtin_amdgcn_global_load_lds(
                    (gvoid_t*)(wsrc + (size_t)(n0 + r) * 1024 + k0 + sc * 8),
                    (lvoid_t*)(wdst + id * 8), 16, 0, 0);
            }
            int rr = tid >> 1, half = tid & 1;
            const float* xp = xf + (size_t)(m0 + rr) * 1024 + k0 + half * 32;
            float fa[32];
            #pragma unroll
            for (int q = 0; q < 8; q++)
                *reinterpret_cast<float4*>(&fa[q * 4]) =
                    reinterpret_cast<const float4*>(xp)[q];
            #pragma unroll
            for (int c = 0; c < 4; c++) {
                short8 hi8, lo8;
                #pragma unroll
                for (int jj = 0; jj < 8; jj++) {
                    u16 h_, l_;
                    split_bf(fa[c * 8 + jj], h_, l_);
                    hi8[jj] = (short)h_; lo8[jj] = (short)l_;
                }
                int cc = half * 4 + c;
                int sc = cc ^ (rr & 7);
                *reinterpret_cast<short8*>(&Xhs[rr * 64 + sc * 8]) = hi8;
                *reinterpret_cast<short8*>(&Xls[rr * 64 + sc * 8]) = lo8;
            }
        } else {
            const u16* src = (w == 0) ? WThi : (w == 1) ? WTlo : (w == 2) ? Bhi : Blo;
            u16* dst       = (w == 0) ? Whs  : (w == 1) ? Wls  : (w == 2) ? Xhs : Xls;
            int rbase = (w < 2) ? n0 : m0;
            #pragma unroll
            for (int it = 0; it < 16; it++) {
                int id = (it << 6) | lane;
                int r = id >> 3, c = id & 7;
                int sc = c ^ (r & 7);
                __builtin_amdgcn_global_load_lds(
                    (gvoid_t*)(src + (size_t)(rbase + r) * 1024 + k0 + sc * 8),
                    (lvoid_t*)(dst + id * 8), 16, 0, 0);
            }
        }
        __syncthreads();

        #pragma unroll
        for (int ks = 0; ks < 2; ks++) {
            short8 ah[4], al[4], bh[4], bl[4];
            #pragma unroll
            for (int i = 0; i < 4; i++) {
                int rn = wn + i * 16 + l15;
                int ch = ((ks << 2) + lg) ^ (rn & 7);
                ah[i] = *reinterpret_cast<const short8*>(&Whs[rn * 64 + ch * 8]);
                al[i] = *reinterpret_cast<const short8*>(&Wls[rn * 64 + ch * 8]);
            }
            #pragma unroll
            for (int j = 0; j < 4; j++) {
                int rm = wm + j * 16 + l15;
                int ch = ((ks << 2) + lg) ^ (rm & 7);
                bh[j] = *reinterpret_cast<const short8*>(&Xhs[rm * 64 + ch * 8]);
                bl[j] = *reinterpret_cast<const short8*>(&Xls[rm * 64 + ch * 8]);
            }
            #pragma unroll
            for (int i = 0; i < 4; i++)
                #pragma unroll
                for (int j = 0; j < 4; j++) {
                    acc[i][j] = mfma16(ah[i], bh[j], acc[i][j]);
                    acc[i][j] = mfma16(ah[i], bl[j], acc[i][j]);
                    acc[i][j] = mfma16(al[i], bh[j], acc[i][j]);
                    acc[i][j] = mfma16(al[i], bl[j], acc[i][j]);
                }
        }
    }

    if constexpr (QKV) {
        #pragma unroll
        for (int i = 0; i < 4; i++) {
            int nb = n0 + wn + i * 16 + lg * 4;
            if (nb < DM) {
                int hh = nb >> 6, d0 = nb & 63;
                #pragma unroll
                for (int j = 0; j < 4; j++) {
                    int m = m0 + wm + j * 16 + l15;
                    int bb = m >> 11, t = m & (SEQ - 1);
                    float4 c4 = *reinterpret_cast<const float4*>(&cosb[t * HD + d0]);
                    float4 s4 = *reinterpret_cast<const float4*>(&sinb[t * HD + d0]);
                    f32x4 a = acc[i][j];
                    float r0 = (a[0] * c4.x - a[1] * s4.x) * 0.125f;
                    float r1 = (a[1] * c4.x + a[0] * s4.x) * 0.125f;
                    float r2 = (a[2] * c4.z - a[3] * s4.z) * 0.125f;
                    float r3 = (a[3] * c4.z + a[2] * s4.z) * 0.125f;
                    u16 h0, l0, h1, l1, h2, l2, h3, l3;
                    split_bf(r0, h0, l0); split_bf(r1, h1, l1);
                    split_bf(r2, h2, l2); split_bf(r3, h3, l3);
                    size_t off = ((size_t)(bb * NQH + hh) * SEQ + t) * HD + d0;
                    *reinterpret_cast<u16x4*>(&Qhi[off]) = u16x4{h0, h1, h2, h3};
                    *reinterpret_cast<u16x4*>(&Qlo[off]) = u16x4{l0, l1, l2, l3};
                }
            } else {
                int rem = nb - DM;
                int kvh = rem >> 7, r2v = rem & 127;
                if (r2v < HD) {
                    int d0 = r2v;
                    #pragma unroll
                    for (int j = 0; j < 4; j++) {
                        int m = m0 + wm + j * 16 + l15;
                        int bb = m >> 11, t = m & (SEQ - 1);
                        float4 c4 = *reinterpret_cast<const float4*>(&cosb[t * HD + d0]);
                        float4 s4 = *reinterpret_cast<const float4*>(&sinb[t * HD + d0]);
                        f32x4 a = acc[i][j];
                        float r0 = a[0] * c4.x - a[1] * s4.x;
                        float r1 = a[1] * c4.x + a[0] * s4.x;
                        float r2 = a[2] * c4.z - a[3] * s4.z;
                        float r3 = a[3] * c4.z + a[2] * s4.z;
                        u16 h0, l0, h1, l1, h2, l2, h3, l3;
                        split_bf(r0, h0, l0); split_bf(r1, h1, l1);
                        split_bf(r2, h2, l2); split_bf(r3, h3, l3);
                        size_t off = ((size_t)(bb * NKVH + kvh) * SEQ + t) * HD + d0;
                        *reinterpret_cast<u16x4*>(&Khi[off]) = u16x4{h0, h1, h2, h3};
                        *reinterpret_cast<u16x4*>(&Klo[off]) = u16x4{l0, l1, l2, l3};
                    }
                } else {
                    int d0 = r2v - HD;
                    #pragma unroll
                    for (int j = 0; j < 4; j++) {
                        int m = m0 + wm + j * 16 + l15;
                        int bb = m >> 11, t = m & (SEQ - 1);
                        size_t vb = (size_t)(bb * NKVH + kvh) * HD;
                        #pragma unroll
                        for (int reg = 0; reg < 4; reg++) {
                            u16 hv, lv;
                            split_bf(acc[i][j][reg], hv, lv);
                            size_t off = (vb + d0 + reg) * SEQ + t;
                            Vthi[off] = hv; Vtlo[off] = lv;
                        }
                    }
                }
            }
        }
    } else {
        #pragma unroll
        for (int i = 0; i < 4; i++) {
            int nb = n0 + wn + i * 16 + lg * 4;
            #pragma unroll
            for (int j = 0; j < 4; j++) {
                int m = m0 + wm + j * 16 + l15;
                *reinterpret_cast<float4*>(&out[(size_t)m * DM + nb]) =
                    make_float4(acc[i][j][0], acc[i][j][1], acc[i][j][2], acc[i][j][3]);
            }
        }
    }
}

// ---------------------------------------------------------------------------
// MFMA flash attention, split-bf16 4-product, swapped QK^T (in-register
// softmax: lane owns q-row l15, 64 kv in-reg, 2+2 shfl_xor reductions).
// ---------------------------------------------------------------------------
__global__ __launch_bounds__(256)
void attn_kernel(const u16* __restrict__ Qhi, const u16* __restrict__ Qlo,
                 const u16* __restrict__ Khi, const u16* __restrict__ Klo,
                 const u16* __restrict__ Vthi, const u16* __restrict__ Vtlo,
                 u16* __restrict__ AOhi, u16* __restrict__ AOlo)
{
    __shared__ __align__(16) u16 Kh[64 * 64];
    __shared__ __align__(16) u16 Kl[64 * 64];
    __shared__ __align__(16) u16 Vh[64 * 64];
    __shared__ __align__(16) u16 Vl[64 * 64];
    __shared__ __align__(16) unsigned int Pb[4][16 * 64];

    const int tid  = threadIdx.x;
    const int lane = tid & 63;
    const int w    = tid >> 6;
    const int l15  = lane & 15;
    const int lg   = lane >> 4;

    const int qt  = blockIdx.x;
    const int bh  = blockIdx.y;
    const int bb  = bh >> 4, h = bh & 15;
    const int kvh = h >> 2;

    const size_t qoff = ((size_t)(bb * NQH + h) * SEQ + qt * 64 + w * 16 + l15) * HD + lg * 8;
    short8 qh[2], ql[2];
    qh[0] = *reinterpret_cast<const short8*>(Qhi + qoff);
    qh[1] = *reinterpret_cast<const short8*>(Qhi + qoff + 32);
    ql[0] = *reinterpret_cast<const short8*>(Qlo + qoff);
    ql[1] = *reinterpret_cast<const short8*>(Qlo + qoff + 32);

    const u16* gb = (w == 0) ? Khi : (w == 1) ? Klo : (w == 2) ? Vthi : Vtlo;
    u16* lb       = (w == 0) ? Kh  : (w == 1) ? Kl  : (w == 2) ? Vh   : Vl;
    const bool isK = (w < 2);
    const size_t ktstep = isK ? (size_t)(64 * HD) : (size_t)64;
    size_t loff[8];
    {
        size_t kb = (size_t)(bb * NKVH + kvh) * SEQ;
        size_t vb = (size_t)(bb * NKVH + kvh) * HD;
        #pragma unroll
        for (int it = 0; it < 8; it++) {
            int nn = it * 64 + lane;
            int r  = nn >> 3, c = nn & 7;
            int sc = c ^ (r & 7);
            loff[it] = isK ? ((kb + r) * (size_t)HD + sc * 8)
                           : ((vb + r) * (size_t)SEQ + sc * 8);
        }
    }

    f32x4 oA[4] = {{0,0,0,0},{0,0,0,0},{0,0,0,0},{0,0,0,0}};
    float mstate = -1e30f;   // running max for q-row = l15
    float lstate = 0.f;      // running denom for q-row = l15

    for (int kt = 0; kt < SEQ / 64; kt++) {
        __syncthreads();
        #pragma unroll
        for (int it = 0; it < 8; it++) {
            __builtin_amdgcn_global_load_lds(
                (gvoid_t*)(gb + loff[it] + (size_t)kt * ktstep),
                (lvoid_t*)(lb + it * 512), 16, 0, 0);
        }
        __syncthreads();

        // ---- S^T = K Q^T (4-product split): kv = ct*16+lg*4+reg, q = l15 ----
        f32x4 sA[4];
        #pragma unroll
        for (int ct = 0; ct < 4; ct++) {
            f32x4 s = {0.f, 0.f, 0.f, 0.f};
            #pragma unroll
            for (int ks = 0; ks < 2; ks++) {
                int r = ct * 16 + l15;
                int c = (ks * 4 + lg) ^ (r & 7);
                short8 kh = *reinterpret_cast<const short8*>(Kh + r * 64 + c * 8);
                short8 kl = *reinterpret_cast<const short8*>(Kl + r * 64 + c * 8);
                s = mfma16(kh, qh[ks], s);
                s = mfma16(kh, ql[ks], s);
                s = mfma16(kl, qh[ks], s);
                s = mfma16(kl, ql[ks], s);
            }
            sA[ct] = s;
        }

        // ---- in-register online softmax (lane owns q-row l15) ----
        float tmx = sA[0][0];
        #pragma unroll
        for (int ct = 0; ct < 4; ct++)
            #pragma unroll
            for (int r = 0; r < 4; r++) tmx = fmaxf(tmx, sA[ct][r]);
        tmx = fmaxf(tmx, __shfl_xor(tmx, 16));
        tmx = fmaxf(tmx, __shfl_xor(tmx, 32));
        float mnew = fmaxf(mstate, tmx);
        float corr = __expf(mstate - mnew);
        mstate = mnew;

        float ps = 0.f;
        u32x4 pk[4];
        #pragma unroll
        for (int ct = 0; ct < 4; ct++) {
            #pragma unroll
            for (int r = 0; r < 4; r++) {
                float p = __expf(sA[ct][r] - mnew);
                ps += p;
                unsigned int hb = bf_rne(p);
                pk[ct][r] = hb | (bf_rne(p - from_bf(hb)) << 16);
            }
        }
        ps += __shfl_xor(ps, 16);
        ps += __shfl_xor(ps, 32);
        lstate = lstate * corr + ps;

        // P -> Pb, swizzled 16B writes (row l15, cols ct*16+lg*4..+3)
        #pragma unroll
        for (int ct = 0; ct < 4; ct++) {
            int c8 = ct * 2 + (lg >> 1);
            int colS = ((c8 ^ (l15 & 7)) << 3) | ((lg & 1) << 2);
            *reinterpret_cast<u32x4*>(&Pb[w][l15 * 64 + colS]) = pk[ct];
        }

        // O rescale: corr for PV rows q = lg*4+rr (pull from lane l15 = lg*4+rr)
        #pragma unroll
        for (int rr = 0; rr < 4; rr++) {
            float c4 = __shfl(corr, lg * 4 + rr, 16);
            oA[0][rr] *= c4; oA[1][rr] *= c4; oA[2][rr] *= c4; oA[3][rr] *= c4;
        }

        // ---- PV: A = P (rows l15 from Pb), B = Vt (4-product) ----
        short8 pah[2], pal[2];
        #pragma unroll
        for (int ks = 0; ks < 2; ks++) {
            int colS = (ks * 32 + lg * 8) ^ ((l15 & 7) << 3);
            const u32x4* pp = reinterpret_cast<const u32x4*>(&Pb[w][l15 * 64 + colS]);
            u32x4 u0 = pp[0], u1 = pp[1];
            #pragma unroll
            for (int j = 0; j < 4; j++) {
                pah[ks][j]     = (short)(u0[j] & 0xffffu);
                pal[ks][j]     = (short)(u0[j] >> 16);
                pah[ks][4 + j] = (short)(u1[j] & 0xffffu);
                pal[ks][4 + j] = (short)(u1[j] >> 16);
            }
        }
        #pragma unroll
        for (int dt = 0; dt < 4; dt++) {
            f32x4 o = oA[dt];
            #pragma unroll
            for (int ks = 0; ks < 2; ks++) {
                int d = dt * 16 + l15;
                int c = (ks * 4 + lg) ^ (d & 7);
                short8 vh = *reinterpret_cast<const short8*>(Vh + d * 64 + c * 8);
                short8 vl = *reinterpret_cast<const short8*>(Vl + d * 64 + c * 8);
                o = mfma16(pah[ks], vh, o);
                o = mfma16(pah[ks], vl, o);
                o = mfma16(pal[ks], vh, o);
                o = mfma16(pal[ks], vl, o);
            }
            oA[dt] = o;
        }
    }

    // epilogue: O row = lg*4+rr; pull denom from lane l15 = lg*4+rr
    #pragma unroll
    for (int rr = 0; rr < 4; rr++) {
        float lfin = __shfl(lstate, lg * 4 + rr, 16);
        float inv = 1.f / lfin;
        int qrow = qt * 64 + w * 16 + lg * 4 + rr;
        size_t off = ((size_t)bb * SEQ + qrow) * DM + h * 64 + l15;
        #pragma unroll
        for (int dt = 0; dt < 4; dt++) {
            float v = oA[dt][rr] * inv;
            unsigned int hb = bf_rne(v);
            AOhi[off + dt * 16] = (u16)hb;
            AOlo[off + dt * 16] = (u16)bf_rne(v - from_bf(hb));
        }
    }
}

// ---------------------------------------------------------------------------
extern "C" void kernel_launch(void* const* d_in, const int* in_sizes, int n_in,
                              void* d_out, int out_size, void* d_ws, size_t ws_size,
                              hipStream_t stream)
{
    const float* x    = (const float*)d_in[0];
    const float* cosb = (const float*)d_in[1];
    const float* sinb = (const float*)d_in[2];
    const float* Wq   = (const float*)d_in[3];
    const float* Wkv  = (const float*)d_in[4];
    const float* Wo   = (const float*)d_in[5];
    float* out = (float*)d_out;

    u16* base  = (u16*)d_ws;
    u16* AOhi  = base;
    u16* AOlo  = base + 8388608;
    u16* WThi  = base;                      // alias over AO region
    u16* WTlo  = base + 1572864;
    u16* Qhi   = base + 16777216;
    u16* Qlo   = base + 25165824;
    u16* WoThi = base + 16777216;           // alias over Q region (post-attn)
    u16* WoTlo = base + 17825792;
    u16* Khi   = base + 33554432;
    u16* Klo   = base + 35651584;
    u16* Vthi  = base + 37748736;
    u16* Vtlo  = base + 39845888;

    tsplit_kernel<<<dim3(16, 16), 256, 0, stream>>>(Wq, 1024, WThi, WTlo);
    tsplit_kernel<<<dim3(16, 8),  256, 0, stream>>>(Wkv, 512, WThi + 1048576, WTlo + 1048576);

    gemm_mfma<true><<<dim3(12, 64), 256, 0, stream>>>(
        x, WThi, WTlo, nullptr, nullptr, cosb, sinb,
        Qhi, Qlo, Khi, Klo, Vthi, Vtlo, nullptr);

    attn_kernel<<<dim3(32, 64), 256, 0, stream>>>(
        Qhi, Qlo, Khi, Klo, Vthi, Vtlo, AOhi, AOlo);

    tsplit_kernel<<<dim3(16, 16), 256, 0, stream>>>(Wo, 1024, WoThi, WoTlo);

    gemm_mfma<false><<<dim3(8, 64), 256, 0, stream>>>(
        nullptr, WoThi, WoTlo, AOhi, AOlo, nullptr, nullptr,
        nullptr, nullptr, nullptr, nullptr, nullptr, nullptr, out);
}